// Round 4
// baseline (279.180 us; speedup 1.0000x reference)
//
#include <hip/hip_runtime.h>
#include <hip/hip_bf16.h>

typedef unsigned short ushort_t;
typedef __attribute__((ext_vector_type(8))) short short8;
typedef __attribute__((ext_vector_type(4))) float floatx4;

#define LOG2E 1.4426950408889634f

__device__ __forceinline__ unsigned short f2bf(float f) {
    unsigned u = __float_as_uint(f);
    u += 0x7FFF + ((u >> 16) & 1);   // RNE
    return (unsigned short)(u >> 16);
}

__device__ __forceinline__ void async_ld16(const void* gptr, void* lptr) {
    typedef const __attribute__((address_space(1))) unsigned int TG;
    typedef __attribute__((address_space(3))) unsigned int TL;
    __builtin_amdgcn_global_load_lds((TG*)(unsigned long long)gptr,
                                     (TL*)(unsigned)(unsigned long long)lptr,
                                     16, 0, 0);
}

// ---------------- fused prep: x->bf16 | w_qkv transpose | w_proj transpose ----------------
__global__ __launch_bounds__(256) void prep_kernel(const float* __restrict__ x,
                                                   const float* __restrict__ wqkv,
                                                   const float* __restrict__ wproj,
                                                   ushort_t* __restrict__ xb,
                                                   ushort_t* __restrict__ wqkvT,
                                                   ushort_t* __restrict__ wprojT) {
    __shared__ float t[32][33];
    int bx = blockIdx.x;
    if (bx < 8192) {
        int i = bx * 256 + threadIdx.x;
        float4 v = ((const float4*)x)[i];
        unsigned long long r = (unsigned long long)f2bf(v.x)
                             | ((unsigned long long)f2bf(v.y) << 16)
                             | ((unsigned long long)f2bf(v.z) << 32)
                             | ((unsigned long long)f2bf(v.w) << 48);
        ((unsigned long long*)xb)[i] = r;
        return;
    }
    const float* in; ushort_t* out; int R, C, bidx;
    if (bx < 8192 + 3072) { in = wqkv; out = wqkvT; R = 1024; C = 3072; bidx = bx - 8192; }
    else                  { in = wproj; out = wprojT; R = 1024; C = 1024; bidx = bx - 11264; }
    int nbc = C >> 5;
    int bc = bidx % nbc, br = bidx / nbc;
    int tx = threadIdx.x & 31, ty = threadIdx.x >> 5;   // 32 x 8
    int r0 = br << 5, c0 = bc << 5;
#pragma unroll
    for (int j = 0; j < 4; ++j)
        t[ty + j * 8][tx] = in[(size_t)(r0 + ty + j * 8) * C + c0 + tx];
    __syncthreads();
#pragma unroll
    for (int j = 0; j < 4; ++j)
        out[(size_t)(c0 + ty + j * 8) * R + r0 + tx] = f2bf(t[tx][ty + j * 8]);
}

// ---------------- QKV GEMM: 128x256 tile, BK=64, counted-vmcnt pipeline, 16 waves ---------
// Grid = 64 x 12 = 768 blocks = exactly 3 rounds on 256 CUs (zero tail). 1024 thr = 16 waves
// (4M x 4N), wave owns 32x64 (acc[2][4] = 32 VGPR -> fits 4 waves/SIMD, <=128 VGPR cap).
// vs R3: doubled waves/SIMD (2->4) to fix latency-bound profile (MfmaUtil 26%, Occ 18%).
// LDS 96 KB: A dbuf 2x[128][64] + B dbuf 2x[256][64]; 1 block/CU.
// Per K-tile: 2 phases x 8 MFMA/wave, vmcnt(3) once per tile (next tile's A+2B in flight),
// T2 chunk-XOR swizzle (pre-swizzled global source, linear LDS dest), T5 setprio,
// XCD-bijective swizzle (768 % 8 == 0). Region overwrite only after its reads were issued
// in the same phase (pattern race-validated in R1-R3 runs).
__global__ __launch_bounds__(1024) void gemm_qkv_kernel(const ushort_t* __restrict__ A,
                                                        const ushort_t* __restrict__ Bt,
                                                        const float* __restrict__ bias,
                                                        ushort_t* __restrict__ qbuf,
                                                        ushort_t* __restrict__ kbuf,
                                                        ushort_t* __restrict__ vtbuf) {
    extern __shared__ __align__(16) ushort_t lds[];
    // regions (ushort idx): A0 @0, A1 @8192, B0 @16384, B1 @32768

    int bid = blockIdx.x;
    int wg = (bid & 7) * 96 + (bid >> 3);      // XCD-bijective swizzle (768 % 8 == 0)
    int bm = wg & 63, bn = wg >> 6;            // 64 x 12
    int m0 = bm << 7, n0 = bn << 8;

    int tid = threadIdx.x;
    int wave = tid >> 6, lane = tid & 63;
    int c = lane & 15, g = lane >> 4;
    int wm = wave >> 2, wn = wave & 3;         // wave = 32 rows (wm) x 64 cols (wn)

    // staging: thread covers one row-chunk per region; global source chunk XOR'd by row&7,
    // LDS dest linear (read side applies same XOR).
    int row0 = tid >> 3;                       // 0..127
    int sch  = (tid & 7) ^ (row0 & 7);
    size_t aoff = (size_t)(m0 + row0) * 1024 + sch * 8;
    size_t boff = (size_t)(n0 + row0) * 1024 + sch * 8;

    int co0 = (g * 8) ^ ((c & 7) << 3);
    int co1 = co0 ^ 32;

    floatx4 acc[2][4];
    short8 a[2][2], bf[2][2], bg[2][2];
#pragma unroll
    for (int i2 = 0; i2 < 2; ++i2)
#pragma unroll
        for (int j2 = 0; j2 < 4; ++j2) { floatx4 z = {0.f,0.f,0.f,0.f}; acc[i2][j2] = z; }

    auto stA = [&](int t, int buf) {           // 16 KB A-tile, 1 load/thread
        async_ld16(A + aoff + (size_t)t * 64, lds + buf * 8192 + tid * 8);
    };
    auto stB = [&](int t, int buf) {           // 32 KB B-tile, 2 loads/thread
        const ushort_t* s = Bt + boff + (size_t)t * 64;
        ushort_t* d = lds + 16384 + buf * 16384 + tid * 8;
        async_ld16(s, d);
        async_ld16(s + 131072, d + 8192);      // rows +128
    };
    auto ld_a = [&](int buf) {
#pragma unroll
        for (int mi = 0; mi < 2; ++mi) {
            int ro = buf * 8192 + (wm * 32 + mi * 16 + c) * 64;
            a[mi][0] = *(const short8*)&lds[ro + co0];
            a[mi][1] = *(const short8*)&lds[ro + co1];
        }
    };
    auto ld_b = [&](int buf, int q, short8 (&bb)[2][2]) {
#pragma unroll
        for (int nii = 0; nii < 2; ++nii) {
            int ro = 16384 + buf * 16384 + (wn * 64 + (q * 2 + nii) * 16 + c) * 64;
            bb[nii][0] = *(const short8*)&lds[ro + co0];
            bb[nii][1] = *(const short8*)&lds[ro + co1];
        }
    };
    auto phase_mm = [&](int q, short8 (&bb)[2][2]) {
        asm volatile("s_barrier" ::: "memory");
        asm volatile("s_waitcnt lgkmcnt(0)" ::: "memory");
        __builtin_amdgcn_s_setprio(1);
#pragma unroll
        for (int mi = 0; mi < 2; ++mi)
#pragma unroll
            for (int nii = 0; nii < 2; ++nii)
#pragma unroll
                for (int ks = 0; ks < 2; ++ks)
                    acc[mi][q * 2 + nii] =
                        __builtin_amdgcn_mfma_f32_16x16x32_bf16(
                            a[mi][ks], bb[nii][ks], acc[mi][q * 2 + nii], 0, 0, 0);
        __builtin_amdgcn_s_setprio(0);
        asm volatile("s_barrier" ::: "memory");
    };

    // prologue: tile0 (3 loads) + tile1 (3 loads); wait tile0, keep tile1 in flight.
    stA(0, 0); stB(0, 0);
    stA(1, 1); stB(1, 1);
    asm volatile("s_waitcnt vmcnt(3)" ::: "memory");
    asm volatile("s_barrier" ::: "memory");

#pragma unroll 1
    for (int i = 0; i < 14; ++i) {
        int buf = i & 1;
        ld_a(buf); ld_b(buf, 0, bf);
        stA(i + 2, buf);                       // A[buf]: reads issued above
        phase_mm(0, bf);
        ld_b(buf, 1, bg);
        stB(i + 2, buf);                       // B[buf]: reads issued above
        asm volatile("s_waitcnt vmcnt(3)" ::: "memory");   // tile i+1 complete
        phase_mm(1, bg);
    }
    // ---- tile 14 (buf 0) ----
    ld_a(0); ld_b(0, 0, bf);
    phase_mm(0, bf);
    ld_b(0, 1, bg);
    asm volatile("s_waitcnt vmcnt(0)" ::: "memory");       // tile 15 complete
    phase_mm(1, bg);
    // ---- tile 15 (buf 1) ----
    ld_a(1); ld_b(1, 0, bf);
    phase_mm(0, bf);
    ld_b(1, 1, bg);
    phase_mm(1, bg);

    // ---------------- epilogue: restage C-tile (128x256) through LDS, split Q/K/Vt -------
    int sec = n0 >> 10;               // 0=Q 1=K 2=V (256-col tile never crosses 1024)
    int h0 = (n0 & 1023) >> 6;        // first of 4 heads in this tile; head = h0 + wn
    int b  = m0 >> 11, sbase = m0 & 2047;
    int bh0 = b * 16 + h0;
    float bv[4];
#pragma unroll
    for (int ni = 0; ni < 4; ++ni) bv[ni] = bias[n0 + wn * 64 + ni * 16 + c];

    __syncthreads();                  // loop drained; reuse LDS for staging

    if (sec < 2) {
        // stage [head][row 128][col 64], row stride 72 (16B-aligned rows): 73.7 KB
        float scl = (sec == 0) ? (0.125f * LOG2E) : 1.0f;
#pragma unroll
        for (int mi = 0; mi < 2; ++mi)
#pragma unroll
            for (int ni = 0; ni < 4; ++ni)
#pragma unroll
                for (int r = 0; r < 4; ++r) {
                    int row = wm * 32 + mi * 16 + g * 4 + r;
                    lds[wn * 9216 + row * 72 + ni * 16 + c] =
                        f2bf((acc[mi][ni][r] + bv[ni]) * scl);
                }
        __syncthreads();
        // copy: thread -> half a row (32 cols = 64 B contiguous in global)
        ushort_t* dstbase = (sec == 0 ? qbuf : kbuf);
        int head = tid >> 8, row = (tid >> 1) & 127, half = tid & 1;
        const ushort_t* src = &lds[head * 9216 + row * 72 + half * 32];
        ushort_t* dst = dstbase + (size_t)(bh0 + head) * 131072
                      + (size_t)(sbase + row) * 64 + half * 32;
#pragma unroll
        for (int j = 0; j < 4; ++j)
            *(short8*)(dst + j * 8) = *(const short8*)(src + j * 8);
    } else {
        // stage [head][d 64][s 128], d stride 136; packed u64 along s: 69.6 KB
#pragma unroll
        for (int mi = 0; mi < 2; ++mi)
#pragma unroll
            for (int ni = 0; ni < 4; ++ni) {
                int d = ni * 16 + c;
                int s0 = wm * 32 + mi * 16 + g * 4;
                unsigned long long pk =
                      (unsigned long long)f2bf(acc[mi][ni][0] + bv[ni])
                    | ((unsigned long long)f2bf(acc[mi][ni][1] + bv[ni]) << 16)
                    | ((unsigned long long)f2bf(acc[mi][ni][2] + bv[ni]) << 32)
                    | ((unsigned long long)f2bf(acc[mi][ni][3] + bv[ni]) << 48);
                *(unsigned long long*)&lds[wn * 8704 + d * 136 + s0] = pk;
            }
        __syncthreads();
        // copy: 4 threads per d-row, 32 s each (64 B contiguous)
        int head = tid >> 8, dd = (tid >> 2) & 63, sq = tid & 3;
        const ushort_t* src = &lds[head * 8704 + dd * 136 + sq * 32];
        ushort_t* dst = vtbuf + (size_t)(bh0 + head) * 131072
                      + (size_t)dd * 2048 + sbase + sq * 32;
#pragma unroll
        for (int j = 0; j < 4; ++j)
            *(short8*)(dst + j * 8) = *(const short8*)(src + j * 8);
    }
}

// ---------------- flash attention: 1 block = (b,h) x 64 q-rows, 64-kp tiles ----------------
// R3 structure (stride-68 LDS, transposed softmax, LPT, reg prefetch, 6 blocks/CU) plus:
// softmax row-sum moved off the VALU onto the idle MFMA pipe — lacc = mfma(pf, ones, lacc)
// accumulates sum_kp P[q][kp] with the SAME C-row mapping (q = g*4+r) the store uses, so the
// 16 fadds/lane/kt AND the end shuffle-reduce disappear. Denominator now sums the identical
// bf16-rounded P used in the numerator (consistent convex combination).
__global__ __launch_bounds__(256, 6) void attn_kernel(const ushort_t* __restrict__ qb_,
                                                      const ushort_t* __restrict__ kb_,
                                                      const ushort_t* __restrict__ vtb_,
                                                      ushort_t* __restrict__ aout) {
    __shared__ __align__(16) ushort_t Ks[64 * 68];       // [kp][d] stride 68
    __shared__ __align__(16) ushort_t Vs[64 * 68];       // [d][kp] stride 68
    __shared__ __align__(16) ushort_t Ps[4][16 * 68];    // per-wave P[q][kp]
    int bx = blockIdx.x;
    int qb = 31 - (bx >> 6);          // LPT: longest blocks dispatch first
    int bhix = bx & 63;
    int b = bhix >> 4, h = bhix & 15;
    int q0 = qb << 6;
    int tid = threadIdx.x, wave = tid >> 6, lane = tid & 63;
    int c = lane & 15, g = lane >> 4;
    size_t bh = (size_t)(b * 16 + h);

    const ushort_t* Qp = qb_ + (bh * 2048 + q0) * 64;
    const ushort_t* Kp = kb_ + bh * 131072;
    const ushort_t* Vp = vtb_ + bh * 131072;

    int qr = wave * 16 + c;
    short8 qf0 = *(const short8*)(Qp + qr * 64 + g * 8);
    short8 qf1 = *(const short8*)(Qp + qr * 64 + 32 + g * 8);

    short8 vones;
#pragma unroll
    for (int j = 0; j < 8; ++j) vones[j] = (short)0x3F80;   // bf16 1.0

    floatx4 o_acc[4];
    floatx4 lacc = {0.f, 0.f, 0.f, 0.f};
#pragma unroll
    for (int nt = 0; nt < 4; ++nt) { floatx4 z = {0.f,0.f,0.f,0.f}; o_acc[nt] = z; }

    short8 kreg[2], vreg[2];
#pragma unroll
    for (int it = 0; it < 2; ++it) {
        int idx = it * 256 + tid;
        kreg[it] = *(const short8*)(Kp + idx * 8);
        vreg[it] = *(const short8*)(Vp + (idx >> 3) * 2048 + (idx & 7) * 8);
    }

    int qg = q0 + wave * 16 + c;
    for (int kt = 0; kt <= qb; ++kt) {
        int kt0 = kt << 6;
        __syncthreads();
#pragma unroll
        for (int it = 0; it < 2; ++it) {
            int idx = it * 256 + tid;
            *(short8*)&Ks[(idx >> 3) * 68 + (idx & 7) * 8] = kreg[it];
            *(short8*)&Vs[(idx >> 3) * 68 + (idx & 7) * 8] = vreg[it];
        }
        __syncthreads();
        if (kt < qb) {
            int s0 = (kt + 1) << 6;
#pragma unroll
            for (int it = 0; it < 2; ++it) {
                int idx = it * 256 + tid;
                kreg[it] = *(const short8*)(Kp + s0 * 64 + idx * 8);
                vreg[it] = *(const short8*)(Vp + (idx >> 3) * 2048 + s0 + (idx & 7) * 8);
            }
        }
        bool diag = (kt == qb);

#pragma unroll
        for (int nt = 0; nt < 4; ++nt) {
            short8 kf0 = *(const short8*)&Ks[(nt * 16 + c) * 68 + g * 8];
            short8 kf1 = *(const short8*)&Ks[(nt * 16 + c) * 68 + 32 + g * 8];
            floatx4 z = {0.f, 0.f, 0.f, 0.f};
            z = __builtin_amdgcn_mfma_f32_16x16x32_bf16(kf0, qf0, z, 0, 0, 0);
            z = __builtin_amdgcn_mfma_f32_16x16x32_bf16(kf1, qf1, z, 0, 0, 0);

            int kpb = kt0 + nt * 16 + g * 4;
            float p[4];
#pragma unroll
            for (int r = 0; r < 4; ++r) {
                float s = z[r];
                if (diag) s = (kpb + r > qg) ? -1e30f : s;
                p[r] = exp2f(s);
            }
            union { unsigned long long u; __hip_bfloat162 h2[2]; } pk;
            pk.h2[0] = __float22bfloat162_rn(make_float2(p[0], p[1]));
            pk.h2[1] = __float22bfloat162_rn(make_float2(p[2], p[3]));
            *(unsigned long long*)&Ps[wave][c * 68 + nt * 16 + g * 4] = pk.u;
        }

#pragma unroll
        for (int ks = 0; ks < 2; ++ks) {
            short8 pf = *(const short8*)&Ps[wave][c * 68 + ks * 32 + g * 8];
            lacc = __builtin_amdgcn_mfma_f32_16x16x32_bf16(pf, vones, lacc, 0, 0, 0);
#pragma unroll
            for (int nt = 0; nt < 4; ++nt) {
                short8 vf = *(const short8*)&Vs[(nt * 16 + c) * 68 + ks * 32 + g * 8];
                o_acc[nt] = __builtin_amdgcn_mfma_f32_16x16x32_bf16(pf, vf, o_acc[nt], 0, 0, 0);
            }
        }
    }

    // lacc[r] = full row-sum for q = q0 + wave*16 + g*4 + r (duplicated across c) — no shfl.
    float inv[4];
#pragma unroll
    for (int r = 0; r < 4; ++r)
        inv[r] = 1.0f / lacc[r];
#pragma unroll
    for (int nt = 0; nt < 4; ++nt)
#pragma unroll
        for (int r = 0; r < 4; ++r) {
            int q = q0 + wave * 16 + g * 4 + r;
            aout[(size_t)(b * 2048 + q) * 1024 + h * 64 + nt * 16 + c] =
                f2bf(o_acc[nt][r] * inv[r]);
        }
}

// ---------------- proj GEMM: [8192,1024]@[1024,1024]^T + bias -> fp32 ----------------
__global__ __launch_bounds__(256) void gemm_proj_kernel(const ushort_t* __restrict__ A,
                                                        const ushort_t* __restrict__ Bt,
                                                        const float* __restrict__ bias,
                                                        float* __restrict__ Cout) {
    const int K = 1024, N = 1024, nbn = 8;
    __shared__ __align__(16) ushort_t As[128 * 32];
    __shared__ __align__(16) ushort_t Bs[128 * 32];
    int bm = blockIdx.x / nbn, bn = blockIdx.x % nbn;
    int m0 = bm << 7, n0 = bn << 7;
    int tid = threadIdx.x;
    int wave = tid >> 6, lane = tid & 63;
    int c = lane & 15, g = lane >> 4;
    int m_off = (wave & 1) << 6, n_off = (wave >> 1) << 6;
    int ldrow = lane >> 2;
    int ldk   = (lane & 3) << 3;

    floatx4 acc[4][4];
#pragma unroll
    for (int mi = 0; mi < 4; ++mi)
#pragma unroll
        for (int ni = 0; ni < 4; ++ni) {
            floatx4 z = {0.f, 0.f, 0.f, 0.f};
            acc[mi][ni] = z;
        }

    for (int kk = 0; kk < K; kk += 32) {
        __syncthreads();
#pragma unroll
        for (int j = 0; j < 2; ++j) {
            int chunk = wave * 2 + j;
            async_ld16(A  + (size_t)(m0 + chunk * 16 + ldrow) * K + kk + ldk, &As[chunk * 512]);
            async_ld16(Bt + (size_t)(n0 + chunk * 16 + ldrow) * K + kk + ldk, &Bs[chunk * 512]);
        }
        __syncthreads();
        short8 bf[4];
#pragma unroll
        for (int ni = 0; ni < 4; ++ni)
            bf[ni] = *(const short8*)&Bs[(n_off + ni * 16 + c) * 32 + g * 8];
#pragma unroll
        for (int mi = 0; mi < 4; ++mi) {
            short8 af = *(const short8*)&As[(m_off + mi * 16 + c) * 32 + g * 8];
#pragma unroll
            for (int ni = 0; ni < 4; ++ni)
                acc[mi][ni] = __builtin_amdgcn_mfma_f32_16x16x32_bf16(af, bf[ni], acc[mi][ni], 0, 0, 0);
        }
    }

    float bv[4];
#pragma unroll
    for (int ni = 0; ni < 4; ++ni) bv[ni] = bias[n0 + n_off + ni * 16 + c];
#pragma unroll
    for (int mi = 0; mi < 4; ++mi)
#pragma unroll
        for (int ni = 0; ni < 4; ++ni)
#pragma unroll
            for (int r = 0; r < 4; ++r) {
                int row = m0 + m_off + mi * 16 + g * 4 + r;
                int col = n0 + n_off + ni * 16 + c;
                Cout[(size_t)row * N + col] = acc[mi][ni][r] + bv[ni];
            }
}

extern "C" void kernel_launch(void* const* d_in, const int* in_sizes, int n_in,
                              void* d_out, int out_size, void* d_ws, size_t ws_size,
                              hipStream_t stream) {
    const float* x        = (const float*)d_in[0];
    const float* c_attn_w = (const float*)d_in[1];
    const float* c_attn_b = (const float*)d_in[2];
    const float* c_proj_w = (const float*)d_in[3];
    const float* c_proj_b = (const float*)d_in[4];
    float* out = (float*)d_out;

    char* ws = (char*)d_ws;
    ushort_t* xb     = (ushort_t*)(ws);              // 16 MB; reused as attn output 'a'
    ushort_t* wqkvT  = (ushort_t*)(ws + 16777216);   // 6 MB
    ushort_t* wprojT = (ushort_t*)(ws + 23068672);   // 2 MB
    ushort_t* qbuf   = (ushort_t*)(ws + 25165824);   // 16 MB  [bh][s][64]  (pre-scaled)
    ushort_t* kbuf   = (ushort_t*)(ws + 41943040);   // 16 MB  [bh][s][64]
    ushort_t* vtbuf  = (ushort_t*)(ws + 58720256);   // 16 MB  [bh][64][2048]

    static bool s_attr_set = false;
    if (!s_attr_set) {
        (void)hipFuncSetAttribute(reinterpret_cast<const void*>(gemm_qkv_kernel),
                                  hipFuncAttributeMaxDynamicSharedMemorySize, 98304);
        s_attr_set = true;
    }

    prep_kernel<<<12288, 256, 0, stream>>>(x, c_attn_w, c_proj_w, xb, wqkvT, wprojT);
    gemm_qkv_kernel<<<768, 1024, 98304, stream>>>(xb, wqkvT, c_attn_b, qbuf, kbuf, vtbuf);
    attn_kernel<<<2048, 256, 0, stream>>>(qbuf, kbuf, vtbuf, xb);
    gemm_proj_kernel<<<64 * 8, 256, 0, stream>>>(xb, wprojT, c_proj_b, out);
}

// Round 5
// 262.571 us; speedup vs baseline: 1.0633x; 1.0633x over previous
//
#include <hip/hip_runtime.h>
#include <hip/hip_bf16.h>

typedef unsigned short ushort_t;
typedef __attribute__((ext_vector_type(8))) short short8;
typedef __attribute__((ext_vector_type(4))) float floatx4;

#define LOG2E 1.4426950408889634f

__device__ __forceinline__ unsigned short f2bf(float f) {
    unsigned u = __float_as_uint(f);
    u += 0x7FFF + ((u >> 16) & 1);   // RNE
    return (unsigned short)(u >> 16);
}

__device__ __forceinline__ void async_ld16(const void* gptr, void* lptr) {
    typedef const __attribute__((address_space(1))) unsigned int TG;
    typedef __attribute__((address_space(3))) unsigned int TL;
    __builtin_amdgcn_global_load_lds((TG*)(unsigned long long)gptr,
                                     (TL*)(unsigned)(unsigned long long)lptr,
                                     16, 0, 0);
}

// ---------------- fused prep: x->bf16 | w_qkv transpose | w_proj transpose ----------------
__global__ __launch_bounds__(256) void prep_kernel(const float* __restrict__ x,
                                                   const float* __restrict__ wqkv,
                                                   const float* __restrict__ wproj,
                                                   ushort_t* __restrict__ xb,
                                                   ushort_t* __restrict__ wqkvT,
                                                   ushort_t* __restrict__ wprojT) {
    __shared__ float t[32][33];
    int bx = blockIdx.x;
    if (bx < 8192) {
        int i = bx * 256 + threadIdx.x;
        float4 v = ((const float4*)x)[i];
        unsigned long long r = (unsigned long long)f2bf(v.x)
                             | ((unsigned long long)f2bf(v.y) << 16)
                             | ((unsigned long long)f2bf(v.z) << 32)
                             | ((unsigned long long)f2bf(v.w) << 48);
        ((unsigned long long*)xb)[i] = r;
        return;
    }
    const float* in; ushort_t* out; int R, C, bidx;
    if (bx < 8192 + 3072) { in = wqkv; out = wqkvT; R = 1024; C = 3072; bidx = bx - 8192; }
    else                  { in = wproj; out = wprojT; R = 1024; C = 1024; bidx = bx - 11264; }
    int nbc = C >> 5;
    int bc = bidx % nbc, br = bidx / nbc;
    int tx = threadIdx.x & 31, ty = threadIdx.x >> 5;   // 32 x 8
    int r0 = br << 5, c0 = bc << 5;
#pragma unroll
    for (int j = 0; j < 4; ++j)
        t[ty + j * 8][tx] = in[(size_t)(r0 + ty + j * 8) * C + c0 + tx];
    __syncthreads();
#pragma unroll
    for (int j = 0; j < 4; ++j)
        out[(size_t)(c0 + ty + j * 8) * R + r0 + tx] = f2bf(t[tx][ty + j * 8]);
}

// ---------------- QKV GEMM: 128x384 tile, BK=64, counted-vmcnt, 16 waves, zero tail -------
// Grid = 64 M x 8 N = 512 blocks = EXACTLY 2 rounds on 256 CUs. 1024 thr = 16 waves
// (2M x 8N), wave owns 64x48: acc[4][3] = 48 VGPR -> 4 waves/SIMD (<=128 VGPR cap).
// LDS 128 KB: A dbuf 2x[128][64] + B dbuf 2x[384][64]; 1 block/CU.
// Per K-tile: 3 phases x 8 MFMA (one ni-frag each); ALL reads of a buffer are issued before
// that buffer's next staging is issued (tighter than R1's distributed staging); vmcnt(4)
// once per tile (next tile's A+3B in flight). T2 chunk-XOR swizzle (pre-swizzled global
// source, linear LDS dest, same XOR on read), T5 setprio, XCD-bijective swizzle (512%8==0).
// Epilogue: per-head section routing — a 64-col head never crosses a 1024 Q/K/V boundary,
// so tiles spanning sections (n0=768: Q+K; n0=1920: K+V) are handled per head.
__global__ __launch_bounds__(1024) void gemm_qkv_kernel(const ushort_t* __restrict__ A,
                                                        const ushort_t* __restrict__ Bt,
                                                        const float* __restrict__ bias,
                                                        ushort_t* __restrict__ qbuf,
                                                        ushort_t* __restrict__ kbuf,
                                                        ushort_t* __restrict__ vtbuf) {
    extern __shared__ __align__(16) ushort_t lds[];
    // regions (ushort idx): A dbuf @0 (8192 each), B dbuf @16384 (24576 each)

    int bid = blockIdx.x;
    int wg = (bid & 7) * 64 + (bid >> 3);      // XCD-bijective swizzle (512 % 8 == 0)
    int bm = wg & 63, bn = wg >> 6;            // 64 x 8
    int m0 = bm << 7, n0 = bn * 384;

    int tid = threadIdx.x;
    int wave = tid >> 6, lane = tid & 63;
    int c = lane & 15, g = lane >> 4;
    int wm = wave >> 3, wn = wave & 7;         // wave = 64 rows (wm) x 48 cols (wn)

    int row0 = tid >> 3;                       // 0..127
    int sch  = (tid & 7) ^ (row0 & 7);
    size_t aoff = (size_t)(m0 + row0) * 1024 + sch * 8;
    size_t boff = (size_t)(n0 + row0) * 1024 + sch * 8;

    int co0 = (g * 8) ^ ((c & 7) << 3);
    int co1 = co0 ^ 32;

    floatx4 acc[4][3];
    short8 a[4][2], bb[2];
#pragma unroll
    for (int i2 = 0; i2 < 4; ++i2)
#pragma unroll
        for (int j2 = 0; j2 < 3; ++j2) { floatx4 z = {0.f,0.f,0.f,0.f}; acc[i2][j2] = z; }

    auto stA = [&](int t, int buf) {           // 16 KB A-tile, 1 load/thread
        async_ld16(A + aoff + (size_t)t * 64, lds + buf * 8192 + tid * 8);
    };
    auto stB = [&](int t, int buf) {           // 48 KB B-tile, 3 loads/thread
        const ushort_t* s = Bt + boff + (size_t)t * 64;
        ushort_t* d = lds + 16384 + buf * 24576 + tid * 8;
        async_ld16(s, d);
        async_ld16(s + 131072, d + 8192);      // rows +128
        async_ld16(s + 262144, d + 16384);     // rows +256
    };
    auto ld_a = [&](int buf) {
#pragma unroll
        for (int mi = 0; mi < 4; ++mi) {
            int ro = buf * 8192 + (wm * 64 + mi * 16 + c) * 64;
            a[mi][0] = *(const short8*)&lds[ro + co0];
            a[mi][1] = *(const short8*)&lds[ro + co1];
        }
    };
    auto ld_b = [&](int buf, int nii) {
        int ro = 16384 + buf * 24576 + (wn * 48 + nii * 16 + c) * 64;
        bb[0] = *(const short8*)&lds[ro + co0];
        bb[1] = *(const short8*)&lds[ro + co1];
    };
    auto mm = [&](int nii) {
        asm volatile("s_barrier" ::: "memory");
        asm volatile("s_waitcnt lgkmcnt(0)" ::: "memory");
        __builtin_amdgcn_s_setprio(1);
#pragma unroll
        for (int mi = 0; mi < 4; ++mi)
#pragma unroll
            for (int ks = 0; ks < 2; ++ks)
                acc[mi][nii] = __builtin_amdgcn_mfma_f32_16x16x32_bf16(
                    a[mi][ks], bb[ks], acc[mi][nii], 0, 0, 0);
        __builtin_amdgcn_s_setprio(0);
        asm volatile("s_barrier" ::: "memory");
    };

    // prologue: tile0 (4 loads) + tile1 (4 loads); wait tile0, keep tile1 in flight.
    stA(0, 0); stB(0, 0);
    stA(1, 1); stB(1, 1);
    asm volatile("s_waitcnt vmcnt(4)" ::: "memory");
    asm volatile("s_barrier" ::: "memory");

#pragma unroll 1
    for (int t = 0; t < 14; ++t) {
        int buf = t & 1;
        ld_a(buf); ld_b(buf, 0);
        mm(0);
        ld_b(buf, 1);
        mm(1);
        ld_b(buf, 2);                          // last read of this buffer issued...
        stA(t + 2, buf); stB(t + 2, buf);      // ...before its staging is issued
        asm volatile("s_waitcnt vmcnt(4)" ::: "memory");   // tile t+1 complete
        mm(2);
    }
    // ---- tile 14 (buf 0) ----
    ld_a(0); ld_b(0, 0);
    mm(0);
    ld_b(0, 1);
    mm(1);
    ld_b(0, 2);
    asm volatile("s_waitcnt vmcnt(0)" ::: "memory");       // tile 15 complete
    mm(2);
    // ---- tile 15 (buf 1) ----
    ld_a(1); ld_b(1, 0);
    mm(0);
    ld_b(1, 1);
    mm(1);
    ld_b(1, 2);
    mm(2);

    // ---------------- epilogue: per-head restage + section routing ----------------
    int b = m0 >> 11, sbase = m0 & 2047;
    float bv[3], scl[3];
    int headf[3], cinh[3], secf[3];
#pragma unroll
    for (int nii = 0; nii < 3; ++nii) {
        int cb = wn * 48 + nii * 16;           // tile-local frag col base (mult of 16)
        bv[nii]   = bias[n0 + cb + c];
        headf[nii] = cb >> 6;                  // head-local index 0..5
        cinh[nii]  = (cb & 63) + c;            // col within head, 0..63
        secf[nii]  = (n0 + cb) >> 10;          // 0=Q 1=K 2=V (per frag, uniform per wave)
        scl[nii]   = (secf[nii] == 0) ? (0.125f * LOG2E) : 1.0f;
    }

    __syncthreads();                           // loop drained; reuse LDS (6 x 9216 regions)

#pragma unroll
    for (int nii = 0; nii < 3; ++nii) {
        if (secf[nii] < 2) {
            // Q/K head region: [row 128][stride 72]
#pragma unroll
            for (int mi = 0; mi < 4; ++mi)
#pragma unroll
                for (int r = 0; r < 4; ++r) {
                    int row = wm * 64 + mi * 16 + g * 4 + r;
                    lds[headf[nii] * 9216 + row * 72 + cinh[nii]] =
                        f2bf((acc[mi][nii][r] + bv[nii]) * scl[nii]);
                }
        } else {
            // V head region: [d 64][stride 136], u64-packed along s
#pragma unroll
            for (int mi = 0; mi < 4; ++mi) {
                int d = cinh[nii];
                int s0 = wm * 64 + mi * 16 + g * 4;
                unsigned long long pk =
                      (unsigned long long)f2bf(acc[mi][nii][0] + bv[nii])
                    | ((unsigned long long)f2bf(acc[mi][nii][1] + bv[nii]) << 16)
                    | ((unsigned long long)f2bf(acc[mi][nii][2] + bv[nii]) << 32)
                    | ((unsigned long long)f2bf(acc[mi][nii][3] + bv[nii]) << 48);
                *(unsigned long long*)&lds[headf[nii] * 9216 + d * 136 + s0] = pk;
            }
        }
    }
    __syncthreads();

#pragma unroll 1
    for (int hl = 0; hl < 6; ++hl) {
        int colg = n0 + hl * 64;
        int sech = colg >> 10;
        int hg = (colg & 1023) >> 6;
        size_t bh = (size_t)(b * 16 + hg);
        if (sech < 2) {
            // 128 rows x 64 cols; thread -> 16 B contiguous chunk
            int row = tid >> 3, ch = tid & 7;
            ushort_t* dst = (sech == 0 ? qbuf : kbuf) + bh * 131072
                          + (size_t)(sbase + row) * 64 + ch * 8;
            *(short8*)dst = *(const short8*)&lds[hl * 9216 + row * 72 + ch * 8];
        } else {
            // 64 d x 128 s; thread -> 16 B contiguous chunk along s
            int d = tid >> 4, sq = tid & 15;
            ushort_t* dst = vtbuf + bh * 131072 + (size_t)d * 2048 + sbase + sq * 8;
            *(short8*)dst = *(const short8*)&lds[hl * 9216 + d * 136 + sq * 8];
        }
    }
}

// ---------------- flash attention: 1 block = (b,h) x 64 q-rows, 64-kp tiles ----------------
// R4 version (kept): stride-68 LDS, transposed softmax, LPT, reg prefetch, 6 blocks/CU,
// row-sum on the MFMA pipe via ones-operand (removes 16 fadds/lane/kt + end shuffles).
__global__ __launch_bounds__(256, 6) void attn_kernel(const ushort_t* __restrict__ qb_,
                                                      const ushort_t* __restrict__ kb_,
                                                      const ushort_t* __restrict__ vtb_,
                                                      ushort_t* __restrict__ aout) {
    __shared__ __align__(16) ushort_t Ks[64 * 68];       // [kp][d] stride 68
    __shared__ __align__(16) ushort_t Vs[64 * 68];       // [d][kp] stride 68
    __shared__ __align__(16) ushort_t Ps[4][16 * 68];    // per-wave P[q][kp]
    int bx = blockIdx.x;
    int qb = 31 - (bx >> 6);          // LPT: longest blocks dispatch first
    int bhix = bx & 63;
    int b = bhix >> 4, h = bhix & 15;
    int q0 = qb << 6;
    int tid = threadIdx.x, wave = tid >> 6, lane = tid & 63;
    int c = lane & 15, g = lane >> 4;
    size_t bh = (size_t)(b * 16 + h);

    const ushort_t* Qp = qb_ + (bh * 2048 + q0) * 64;
    const ushort_t* Kp = kb_ + bh * 131072;
    const ushort_t* Vp = vtb_ + bh * 131072;

    int qr = wave * 16 + c;
    short8 qf0 = *(const short8*)(Qp + qr * 64 + g * 8);
    short8 qf1 = *(const short8*)(Qp + qr * 64 + 32 + g * 8);

    short8 vones;
#pragma unroll
    for (int j = 0; j < 8; ++j) vones[j] = (short)0x3F80;   // bf16 1.0

    floatx4 o_acc[4];
    floatx4 lacc = {0.f, 0.f, 0.f, 0.f};
#pragma unroll
    for (int nt = 0; nt < 4; ++nt) { floatx4 z = {0.f,0.f,0.f,0.f}; o_acc[nt] = z; }

    short8 kreg[2], vreg[2];
#pragma unroll
    for (int it = 0; it < 2; ++it) {
        int idx = it * 256 + tid;
        kreg[it] = *(const short8*)(Kp + idx * 8);
        vreg[it] = *(const short8*)(Vp + (idx >> 3) * 2048 + (idx & 7) * 8);
    }

    int qg = q0 + wave * 16 + c;
    for (int kt = 0; kt <= qb; ++kt) {
        int kt0 = kt << 6;
        __syncthreads();
#pragma unroll
        for (int it = 0; it < 2; ++it) {
            int idx = it * 256 + tid;
            *(short8*)&Ks[(idx >> 3) * 68 + (idx & 7) * 8] = kreg[it];
            *(short8*)&Vs[(idx >> 3) * 68 + (idx & 7) * 8] = vreg[it];
        }
        __syncthreads();
        if (kt < qb) {
            int s0 = (kt + 1) << 6;
#pragma unroll
            for (int it = 0; it < 2; ++it) {
                int idx = it * 256 + tid;
                kreg[it] = *(const short8*)(Kp + s0 * 64 + idx * 8);
                vreg[it] = *(const short8*)(Vp + (idx >> 3) * 2048 + s0 + (idx & 7) * 8);
            }
        }
        bool diag = (kt == qb);

#pragma unroll
        for (int nt = 0; nt < 4; ++nt) {
            short8 kf0 = *(const short8*)&Ks[(nt * 16 + c) * 68 + g * 8];
            short8 kf1 = *(const short8*)&Ks[(nt * 16 + c) * 68 + 32 + g * 8];
            floatx4 z = {0.f, 0.f, 0.f, 0.f};
            z = __builtin_amdgcn_mfma_f32_16x16x32_bf16(kf0, qf0, z, 0, 0, 0);
            z = __builtin_amdgcn_mfma_f32_16x16x32_bf16(kf1, qf1, z, 0, 0, 0);

            int kpb = kt0 + nt * 16 + g * 4;
            float p[4];
#pragma unroll
            for (int r = 0; r < 4; ++r) {
                float s = z[r];
                if (diag) s = (kpb + r > qg) ? -1e30f : s;
                p[r] = exp2f(s);
            }
            union { unsigned long long u; __hip_bfloat162 h2[2]; } pk;
            pk.h2[0] = __float22bfloat162_rn(make_float2(p[0], p[1]));
            pk.h2[1] = __float22bfloat162_rn(make_float2(p[2], p[3]));
            *(unsigned long long*)&Ps[wave][c * 68 + nt * 16 + g * 4] = pk.u;
        }

#pragma unroll
        for (int ks = 0; ks < 2; ++ks) {
            short8 pf = *(const short8*)&Ps[wave][c * 68 + ks * 32 + g * 8];
            lacc = __builtin_amdgcn_mfma_f32_16x16x32_bf16(pf, vones, lacc, 0, 0, 0);
#pragma unroll
            for (int nt = 0; nt < 4; ++nt) {
                short8 vf = *(const short8*)&Vs[(nt * 16 + c) * 68 + ks * 32 + g * 8];
                o_acc[nt] = __builtin_amdgcn_mfma_f32_16x16x32_bf16(pf, vf, o_acc[nt], 0, 0, 0);
            }
        }
    }

    // lacc[r] = full row-sum for q = q0 + wave*16 + g*4 + r (duplicated across c) — no shfl.
    float inv[4];
#pragma unroll
    for (int r = 0; r < 4; ++r)
        inv[r] = 1.0f / lacc[r];
#pragma unroll
    for (int nt = 0; nt < 4; ++nt)
#pragma unroll
        for (int r = 0; r < 4; ++r) {
            int q = q0 + wave * 16 + g * 4 + r;
            aout[(size_t)(b * 2048 + q) * 1024 + h * 64 + nt * 16 + c] =
                f2bf(o_acc[nt][r] * inv[r]);
        }
}

// ---------------- proj GEMM: 256x128 tile, BK=64, counted-vmcnt, 16 waves, zero tail ------
// Grid = 32 M x 8 N = 256 blocks = EXACTLY 1 round on 256 CUs. 1024 thr = 16 waves (4M x 4N),
// wave owns 64x32: acc[4][2] = 32 VGPR. LDS 96 KB: A dbuf 2x[256][64] + B dbuf 2x[128][64].
// 2 phases/K-tile (8 MFMA each), vmcnt(3) once per tile, chunk-XOR swizzle, setprio.
__global__ __launch_bounds__(1024) void gemm_proj_kernel(const ushort_t* __restrict__ A,
                                                         const ushort_t* __restrict__ Bt,
                                                         const float* __restrict__ bias,
                                                         float* __restrict__ Cout) {
    extern __shared__ __align__(16) ushort_t lds[];
    // regions (ushort idx): A dbuf @0 (16384 each), B dbuf @32768 (8192 each)

    int bid = blockIdx.x;
    int wg = (bid & 7) * 32 + (bid >> 3);      // XCD-bijective swizzle (256 % 8 == 0)
    int bm = wg & 31, bn = wg >> 5;            // 32 x 8
    int m0 = bm << 8, n0 = bn << 7;

    int tid = threadIdx.x;
    int wave = tid >> 6, lane = tid & 63;
    int c = lane & 15, g = lane >> 4;
    int wm = wave >> 2, wn = wave & 3;         // wave = 64 rows (wm) x 32 cols (wn)

    int row0 = tid >> 3;                       // 0..127
    int sch  = (tid & 7) ^ (row0 & 7);
    size_t aoff = (size_t)(m0 + row0) * 1024 + sch * 8;
    size_t boff = (size_t)(n0 + row0) * 1024 + sch * 8;

    int co0 = (g * 8) ^ ((c & 7) << 3);
    int co1 = co0 ^ 32;

    floatx4 acc[4][2];
    short8 a[4][2], bb[2];
#pragma unroll
    for (int i2 = 0; i2 < 4; ++i2)
#pragma unroll
        for (int j2 = 0; j2 < 2; ++j2) { floatx4 z = {0.f,0.f,0.f,0.f}; acc[i2][j2] = z; }

    auto stA = [&](int t, int buf) {           // 32 KB A-tile, 2 loads/thread
        const ushort_t* s = A + aoff + (size_t)t * 64;
        ushort_t* d = lds + buf * 16384 + tid * 8;
        async_ld16(s, d);
        async_ld16(s + 131072, d + 8192);      // rows +128
    };
    auto stB = [&](int t, int buf) {           // 16 KB B-tile, 1 load/thread
        async_ld16(Bt + boff + (size_t)t * 64, lds + 32768 + buf * 8192 + tid * 8);
    };
    auto ld_a = [&](int buf) {
#pragma unroll
        for (int mi = 0; mi < 4; ++mi) {
            int ro = buf * 16384 + (wm * 64 + mi * 16 + c) * 64;
            a[mi][0] = *(const short8*)&lds[ro + co0];
            a[mi][1] = *(const short8*)&lds[ro + co1];
        }
    };
    auto ld_b = [&](int buf, int nii) {
        int ro = 32768 + buf * 8192 + (wn * 32 + nii * 16 + c) * 64;
        bb[0] = *(const short8*)&lds[ro + co0];
        bb[1] = *(const short8*)&lds[ro + co1];
    };
    auto mm = [&](int nii) {
        asm volatile("s_barrier" ::: "memory");
        asm volatile("s_waitcnt lgkmcnt(0)" ::: "memory");
        __builtin_amdgcn_s_setprio(1);
#pragma unroll
        for (int mi = 0; mi < 4; ++mi)
#pragma unroll
            for (int ks = 0; ks < 2; ++ks)
                acc[mi][nii] = __builtin_amdgcn_mfma_f32_16x16x32_bf16(
                    a[mi][ks], bb[ks], acc[mi][nii], 0, 0, 0);
        __builtin_amdgcn_s_setprio(0);
        asm volatile("s_barrier" ::: "memory");
    };

    stA(0, 0); stB(0, 0);
    stA(1, 1); stB(1, 1);
    asm volatile("s_waitcnt vmcnt(3)" ::: "memory");
    asm volatile("s_barrier" ::: "memory");

#pragma unroll 1
    for (int t = 0; t < 14; ++t) {
        int buf = t & 1;
        ld_a(buf); ld_b(buf, 0);
        mm(0);
        ld_b(buf, 1);
        stA(t + 2, buf); stB(t + 2, buf);
        asm volatile("s_waitcnt vmcnt(3)" ::: "memory");   // tile t+1 complete
        mm(1);
    }
    ld_a(0); ld_b(0, 0);
    mm(0);
    ld_b(0, 1);
    asm volatile("s_waitcnt vmcnt(0)" ::: "memory");
    mm(1);
    ld_a(1); ld_b(1, 0);
    mm(0);
    ld_b(1, 1);
    mm(1);

    float bv[2];
#pragma unroll
    for (int nii = 0; nii < 2; ++nii) bv[nii] = bias[n0 + wn * 32 + nii * 16 + c];
#pragma unroll
    for (int mi = 0; mi < 4; ++mi)
#pragma unroll
        for (int nii = 0; nii < 2; ++nii)
#pragma unroll
            for (int r = 0; r < 4; ++r) {
                int row = m0 + wm * 64 + mi * 16 + g * 4 + r;
                int col = n0 + wn * 32 + nii * 16 + c;
                Cout[(size_t)row * 1024 + col] = acc[mi][nii][r] + bv[nii];
            }
}

extern "C" void kernel_launch(void* const* d_in, const int* in_sizes, int n_in,
                              void* d_out, int out_size, void* d_ws, size_t ws_size,
                              hipStream_t stream) {
    const float* x        = (const float*)d_in[0];
    const float* c_attn_w = (const float*)d_in[1];
    const float* c_attn_b = (const float*)d_in[2];
    const float* c_proj_w = (const float*)d_in[3];
    const float* c_proj_b = (const float*)d_in[4];
    float* out = (float*)d_out;

    char* ws = (char*)d_ws;
    ushort_t* xb     = (ushort_t*)(ws);              // 16 MB; reused as attn output 'a'
    ushort_t* wqkvT  = (ushort_t*)(ws + 16777216);   // 6 MB
    ushort_t* wprojT = (ushort_t*)(ws + 23068672);   // 2 MB
    ushort_t* qbuf   = (ushort_t*)(ws + 25165824);   // 16 MB  [bh][s][64]  (pre-scaled)
    ushort_t* kbuf   = (ushort_t*)(ws + 41943040);   // 16 MB  [bh][s][64]
    ushort_t* vtbuf  = (ushort_t*)(ws + 58720256);   // 16 MB  [bh][64][2048]

    static bool s_attr_set = false;
    if (!s_attr_set) {
        (void)hipFuncSetAttribute(reinterpret_cast<const void*>(gemm_qkv_kernel),
                                  hipFuncAttributeMaxDynamicSharedMemorySize, 131072);
        (void)hipFuncSetAttribute(reinterpret_cast<const void*>(gemm_proj_kernel),
                                  hipFuncAttributeMaxDynamicSharedMemorySize, 98304);
        s_attr_set = true;
    }

    prep_kernel<<<12288, 256, 0, stream>>>(x, c_attn_w, c_proj_w, xb, wqkvT, wprojT);
    gemm_qkv_kernel<<<512, 1024, 131072, stream>>>(xb, wqkvT, c_attn_b, qbuf, kbuf, vtbuf);
    attn_kernel<<<2048, 256, 0, stream>>>(qbuf, kbuf, vtbuf, xb);
    gemm_proj_kernel<<<256, 1024, 98304, stream>>>(xb, wprojT, c_proj_b, out);
}

// Round 6
// 255.617 us; speedup vs baseline: 1.0922x; 1.0272x over previous
//
#include <hip/hip_runtime.h>
#include <hip/hip_bf16.h>

typedef unsigned short ushort_t;
typedef __attribute__((ext_vector_type(8))) short short8;
typedef __attribute__((ext_vector_type(4))) float floatx4;
typedef __attribute__((ext_vector_type(16))) float floatx16;

#define LOG2E 1.4426950408889634f

__device__ __forceinline__ unsigned short f2bf(float f) {
    unsigned u = __float_as_uint(f);
    u += 0x7FFF + ((u >> 16) & 1);   // RNE
    return (unsigned short)(u >> 16);
}

__device__ __forceinline__ void async_ld16(const void* gptr, void* lptr) {
    typedef const __attribute__((address_space(1))) unsigned int TG;
    typedef __attribute__((address_space(3))) unsigned int TL;
    __builtin_amdgcn_global_load_lds((TG*)(unsigned long long)gptr,
                                     (TL*)(unsigned)(unsigned long long)lptr,
                                     16, 0, 0);
}

// ---------------- fused prep: x->bf16 | w_qkv transpose | w_proj transpose ----------------
__global__ __launch_bounds__(256) void prep_kernel(const float* __restrict__ x,
                                                   const float* __restrict__ wqkv,
                                                   const float* __restrict__ wproj,
                                                   ushort_t* __restrict__ xb,
                                                   ushort_t* __restrict__ wqkvT,
                                                   ushort_t* __restrict__ wprojT) {
    __shared__ float t[32][33];
    int bx = blockIdx.x;
    if (bx < 8192) {
        int i = bx * 256 + threadIdx.x;
        float4 v = ((const float4*)x)[i];
        unsigned long long r = (unsigned long long)f2bf(v.x)
                             | ((unsigned long long)f2bf(v.y) << 16)
                             | ((unsigned long long)f2bf(v.z) << 32)
                             | ((unsigned long long)f2bf(v.w) << 48);
        ((unsigned long long*)xb)[i] = r;
        return;
    }
    const float* in; ushort_t* out; int R, C, bidx;
    if (bx < 8192 + 3072) { in = wqkv; out = wqkvT; R = 1024; C = 3072; bidx = bx - 8192; }
    else                  { in = wproj; out = wprojT; R = 1024; C = 1024; bidx = bx - 11264; }
    int nbc = C >> 5;
    int bc = bidx % nbc, br = bidx / nbc;
    int tx = threadIdx.x & 31, ty = threadIdx.x >> 5;   // 32 x 8
    int r0 = br << 5, c0 = bc << 5;
#pragma unroll
    for (int j = 0; j < 4; ++j)
        t[ty + j * 8][tx] = in[(size_t)(r0 + ty + j * 8) * C + c0 + tx];
    __syncthreads();
#pragma unroll
    for (int j = 0; j < 4; ++j)
        out[(size_t)(c0 + ty + j * 8) * R + r0 + tx] = f2bf(t[tx][ty + j * 8]);
}

// ---------------- QKV GEMM: 128x384 tile, BK=64, counted-vmcnt, 16 waves, zero tail -------
// (unchanged from R5 — dropped out of top-5)
__global__ __launch_bounds__(1024) void gemm_qkv_kernel(const ushort_t* __restrict__ A,
                                                        const ushort_t* __restrict__ Bt,
                                                        const float* __restrict__ bias,
                                                        ushort_t* __restrict__ qbuf,
                                                        ushort_t* __restrict__ kbuf,
                                                        ushort_t* __restrict__ vtbuf) {
    extern __shared__ __align__(16) ushort_t lds[];

    int bid = blockIdx.x;
    int wg = (bid & 7) * 64 + (bid >> 3);      // XCD-bijective swizzle (512 % 8 == 0)
    int bm = wg & 63, bn = wg >> 6;            // 64 x 8
    int m0 = bm << 7, n0 = bn * 384;

    int tid = threadIdx.x;
    int wave = tid >> 6, lane = tid & 63;
    int c = lane & 15, g = lane >> 4;
    int wm = wave >> 3, wn = wave & 7;         // wave = 64 rows (wm) x 48 cols (wn)

    int row0 = tid >> 3;                       // 0..127
    int sch  = (tid & 7) ^ (row0 & 7);
    size_t aoff = (size_t)(m0 + row0) * 1024 + sch * 8;
    size_t boff = (size_t)(n0 + row0) * 1024 + sch * 8;

    int co0 = (g * 8) ^ ((c & 7) << 3);
    int co1 = co0 ^ 32;

    floatx4 acc[4][3];
    short8 a[4][2], bb[2];
#pragma unroll
    for (int i2 = 0; i2 < 4; ++i2)
#pragma unroll
        for (int j2 = 0; j2 < 3; ++j2) { floatx4 z = {0.f,0.f,0.f,0.f}; acc[i2][j2] = z; }

    auto stA = [&](int t, int buf) {           // 16 KB A-tile, 1 load/thread
        async_ld16(A + aoff + (size_t)t * 64, lds + buf * 8192 + tid * 8);
    };
    auto stB = [&](int t, int buf) {           // 48 KB B-tile, 3 loads/thread
        const ushort_t* s = Bt + boff + (size_t)t * 64;
        ushort_t* d = lds + 16384 + buf * 24576 + tid * 8;
        async_ld16(s, d);
        async_ld16(s + 131072, d + 8192);      // rows +128
        async_ld16(s + 262144, d + 16384);     // rows +256
    };
    auto ld_a = [&](int buf) {
#pragma unroll
        for (int mi = 0; mi < 4; ++mi) {
            int ro = buf * 8192 + (wm * 64 + mi * 16 + c) * 64;
            a[mi][0] = *(const short8*)&lds[ro + co0];
            a[mi][1] = *(const short8*)&lds[ro + co1];
        }
    };
    auto ld_b = [&](int buf, int nii) {
        int ro = 16384 + buf * 24576 + (wn * 48 + nii * 16 + c) * 64;
        bb[0] = *(const short8*)&lds[ro + co0];
        bb[1] = *(const short8*)&lds[ro + co1];
    };
    auto mm = [&](int nii) {
        asm volatile("s_barrier" ::: "memory");
        asm volatile("s_waitcnt lgkmcnt(0)" ::: "memory");
        __builtin_amdgcn_s_setprio(1);
#pragma unroll
        for (int mi = 0; mi < 4; ++mi)
#pragma unroll
            for (int ks = 0; ks < 2; ++ks)
                acc[mi][nii] = __builtin_amdgcn_mfma_f32_16x16x32_bf16(
                    a[mi][ks], bb[ks], acc[mi][nii], 0, 0, 0);
        __builtin_amdgcn_s_setprio(0);
        asm volatile("s_barrier" ::: "memory");
    };

    stA(0, 0); stB(0, 0);
    stA(1, 1); stB(1, 1);
    asm volatile("s_waitcnt vmcnt(4)" ::: "memory");
    asm volatile("s_barrier" ::: "memory");

#pragma unroll 1
    for (int t = 0; t < 14; ++t) {
        int buf = t & 1;
        ld_a(buf); ld_b(buf, 0);
        mm(0);
        ld_b(buf, 1);
        mm(1);
        ld_b(buf, 2);
        stA(t + 2, buf); stB(t + 2, buf);
        asm volatile("s_waitcnt vmcnt(4)" ::: "memory");
        mm(2);
    }
    ld_a(0); ld_b(0, 0);
    mm(0);
    ld_b(0, 1);
    mm(1);
    ld_b(0, 2);
    asm volatile("s_waitcnt vmcnt(0)" ::: "memory");
    mm(2);
    ld_a(1); ld_b(1, 0);
    mm(0);
    ld_b(1, 1);
    mm(1);
    ld_b(1, 2);
    mm(2);

    int b = m0 >> 11, sbase = m0 & 2047;
    float bv[3], scl[3];
    int headf[3], cinh[3], secf[3];
#pragma unroll
    for (int nii = 0; nii < 3; ++nii) {
        int cb = wn * 48 + nii * 16;
        bv[nii]   = bias[n0 + cb + c];
        headf[nii] = cb >> 6;
        cinh[nii]  = (cb & 63) + c;
        secf[nii]  = (n0 + cb) >> 10;
        scl[nii]   = (secf[nii] == 0) ? (0.125f * LOG2E) : 1.0f;
    }

    __syncthreads();

#pragma unroll
    for (int nii = 0; nii < 3; ++nii) {
        if (secf[nii] < 2) {
#pragma unroll
            for (int mi = 0; mi < 4; ++mi)
#pragma unroll
                for (int r = 0; r < 4; ++r) {
                    int row = wm * 64 + mi * 16 + g * 4 + r;
                    lds[headf[nii] * 9216 + row * 72 + cinh[nii]] =
                        f2bf((acc[mi][nii][r] + bv[nii]) * scl[nii]);
                }
        } else {
#pragma unroll
            for (int mi = 0; mi < 4; ++mi) {
                int d = cinh[nii];
                int s0 = wm * 64 + mi * 16 + g * 4;
                unsigned long long pk =
                      (unsigned long long)f2bf(acc[mi][nii][0] + bv[nii])
                    | ((unsigned long long)f2bf(acc[mi][nii][1] + bv[nii]) << 16)
                    | ((unsigned long long)f2bf(acc[mi][nii][2] + bv[nii]) << 32)
                    | ((unsigned long long)f2bf(acc[mi][nii][3] + bv[nii]) << 48);
                *(unsigned long long*)&lds[headf[nii] * 9216 + d * 136 + s0] = pk;
            }
        }
    }
    __syncthreads();

#pragma unroll 1
    for (int hl = 0; hl < 6; ++hl) {
        int colg = n0 + hl * 64;
        int sech = colg >> 10;
        int hg = (colg & 1023) >> 6;
        size_t bh = (size_t)(b * 16 + hg);
        if (sech < 2) {
            int row = tid >> 3, ch = tid & 7;
            ushort_t* dst = (sech == 0 ? qbuf : kbuf) + bh * 131072
                          + (size_t)(sbase + row) * 64 + ch * 8;
            *(short8*)dst = *(const short8*)&lds[hl * 9216 + row * 72 + ch * 8];
        } else {
            int d = tid >> 4, sq = tid & 15;
            ushort_t* dst = vtbuf + bh * 131072 + (size_t)d * 2048 + sbase + sq * 8;
            *(short8*)dst = *(const short8*)&lds[hl * 9216 + d * 136 + sq * 8];
        }
    }
}

// ---------------- flash attention: 32x32 MFMA, in-register softmax, kp-split waves --------
// Block = (b,h) x 64 q-rows; 4 waves = (qh: q-tile of 32) x (kh: kp-half of 32). LDS halved
// vs 16x16 scheme: per kt per wave only kf 4KB + vf 4KB b128 reads (32x32x16 reads half the
// operand bytes per FLOP), P never touches LDS (cvt_pk + shfl_xor(32) word exchange derived
// from the verified 32x32 D-layout row=(r&3)+8*(r>>2)+4*hi). Row-sum via ones-MFMA (R4).
// kp-split partial O/l reduced once at end through a 16KB LDS buffer. (256,4): 34KB LDS.
__global__ __launch_bounds__(256, 4) void attn_kernel(const ushort_t* __restrict__ qb_,
                                                      const ushort_t* __restrict__ kb_,
                                                      const ushort_t* __restrict__ vtb_,
                                                      ushort_t* __restrict__ aout) {
    __shared__ __align__(16) ushort_t Ks[64 * 68];       // [kp][d] stride 68
    __shared__ __align__(16) ushort_t Vs[64 * 68];       // [d][kp] stride 68
    __shared__ __align__(16) float Lo[2][32][64];        // kh=1 partial O
    __shared__ float Ll[2][32];                          // kh=1 partial row-sum
    int bx = blockIdx.x;
    int qb = 31 - (bx >> 6);          // LPT: longest blocks dispatch first
    int bhix = bx & 63;
    int b = bhix >> 4, h = bhix & 15;
    int q0 = qb << 6;
    int tid = threadIdx.x, wave = tid >> 6, lane = tid & 63;
    int qh = wave >> 1, kh = wave & 1;
    int l31 = lane & 31, hi = lane >> 5;
    size_t bh = (size_t)(b * 16 + h);

    const ushort_t* Qp = qb_ + (bh * 2048 + q0 + qh * 32 + l31) * 64;
    const ushort_t* Kp = kb_ + bh * 131072;
    const ushort_t* Vp = vtb_ + bh * 131072;

    // Q as B-operand: col=l31 (q row), k elements d = s*16 + hi*8 + j
    short8 qf[4];
#pragma unroll
    for (int s = 0; s < 4; ++s)
        qf[s] = *(const short8*)(Qp + s * 16 + hi * 8);

    short8 vones;
#pragma unroll
    for (int j = 0; j < 8; ++j) vones[j] = (short)0x3F80;   // bf16 1.0

    floatx16 o0, o1, lacc;
#pragma unroll
    for (int i = 0; i < 16; ++i) { o0[i] = 0.f; o1[i] = 0.f; lacc[i] = 0.f; }

    short8 kreg[2], vreg[2];
#pragma unroll
    for (int it = 0; it < 2; ++it) {
        int idx = it * 256 + tid;
        kreg[it] = *(const short8*)(Kp + idx * 8);
        vreg[it] = *(const short8*)(Vp + (idx >> 3) * 2048 + (idx & 7) * 8);
    }

    int qg = q0 + qh * 32 + l31;
    int krow = (kh * 32 + l31) * 68 + hi * 8;
    for (int kt = 0; kt <= qb; ++kt) {
        int kt0 = kt << 6;
        __syncthreads();
#pragma unroll
        for (int it = 0; it < 2; ++it) {
            int idx = it * 256 + tid;
            *(short8*)&Ks[(idx >> 3) * 68 + (idx & 7) * 8] = kreg[it];
            *(short8*)&Vs[(idx >> 3) * 68 + (idx & 7) * 8] = vreg[it];
        }
        __syncthreads();
        if (kt < qb) {
            int s0 = (kt + 1) << 6;
#pragma unroll
            for (int it = 0; it < 2; ++it) {
                int idx = it * 256 + tid;
                kreg[it] = *(const short8*)(Kp + s0 * 64 + idx * 8);
                vreg[it] = *(const short8*)(Vp + (idx >> 3) * 2048 + s0 + (idx & 7) * 8);
            }
        }
        bool diag = (kt == qb);

        // QK^T: z[kp32][q32], A = K rows (this wave's kp-half), B = Q
        floatx16 z;
#pragma unroll
        for (int i = 0; i < 16; ++i) z[i] = 0.f;
#pragma unroll
        for (int s = 0; s < 4; ++s) {
            short8 kf = *(const short8*)&Ks[krow + s * 16];
            z = __builtin_amdgcn_mfma_f32_32x32x16_bf16(kf, qf[s], z, 0, 0, 0);
        }

        // mask + exp in place: z[r] -> P, kp = kt0 + kh*32 + (r&3)+8*(r>>2)+4*hi, q col = qg
        int kpb_ = kt0 + kh * 32 + 4 * hi;
#pragma unroll
        for (int r = 0; r < 16; ++r) {
            float s = z[r];
            if (diag) s = (kpb_ + (r & 3) + 8 * (r >> 2) > qg) ? -1e30f : s;
            z[r] = exp2f(s);
        }
        // pack to bf16 words: w[t][u2] = P pair at kp = 2*u2 + 8*t + 4*hi
        unsigned w[4][2];
#pragma unroll
        for (int t2 = 0; t2 < 4; ++t2)
#pragma unroll
            for (int u2 = 0; u2 < 2; ++u2) {
                union { unsigned u; __hip_bfloat162 h2; } pk;
                pk.h2 = __float22bfloat162_rn(
                    make_float2(z[t2 * 4 + u2 * 2], z[t2 * 4 + u2 * 2 + 1]));
                w[t2][u2] = pk.u;
            }
        // PV + row-sum: per k-step s (kp base s*16), assemble A-frag via half exchange
#pragma unroll
        for (int s = 0; s < 2; ++s) {
            unsigned s0w = hi ? w[2 * s][0] : w[2 * s + 1][0];
            unsigned s1w = hi ? w[2 * s][1] : w[2 * s + 1][1];
            unsigned r0 = (unsigned)__shfl_xor((int)s0w, 32);
            unsigned r1 = (unsigned)__shfl_xor((int)s1w, 32);
            union { unsigned u[4]; short8 v; } pa;
            if (hi == 0) { pa.u[0] = w[2*s][0]; pa.u[1] = w[2*s][1]; pa.u[2] = r0; pa.u[3] = r1; }
            else         { pa.u[0] = r0; pa.u[1] = r1; pa.u[2] = w[2*s+1][0]; pa.u[3] = w[2*s+1][1]; }
            short8 vb0 = *(const short8*)&Vs[l31 * 68 + kh * 32 + s * 16 + hi * 8];
            short8 vb1 = *(const short8*)&Vs[(32 + l31) * 68 + kh * 32 + s * 16 + hi * 8];
            o0   = __builtin_amdgcn_mfma_f32_32x32x16_bf16(pa.v, vb0,   o0,   0, 0, 0);
            o1   = __builtin_amdgcn_mfma_f32_32x32x16_bf16(pa.v, vb1,   o1,   0, 0, 0);
            lacc = __builtin_amdgcn_mfma_f32_32x32x16_bf16(pa.v, vones, lacc, 0, 0, 0);
        }
    }

    // cross-kp-half reduction: kh=1 writes partials, kh=0 adds, normalizes, stores.
    if (kh == 1) {
#pragma unroll
        for (int r = 0; r < 16; ++r) {
            int q = (r & 3) + 8 * (r >> 2) + 4 * hi;
            Lo[qh][q][l31]      = o0[r];
            Lo[qh][q][32 + l31] = o1[r];
        }
        if (l31 == 0) {
#pragma unroll
            for (int r = 0; r < 16; ++r)
                Ll[qh][(r & 3) + 8 * (r >> 2) + 4 * hi] = lacc[r];
        }
    }
    __syncthreads();
    if (kh == 0) {
#pragma unroll
        for (int r = 0; r < 16; ++r) {
            int q = (r & 3) + 8 * (r >> 2) + 4 * hi;
            float linv = 1.0f / (lacc[r] + Ll[qh][q]);
            int qgl = q0 + qh * 32 + q;
            size_t base = (size_t)(b * 2048 + qgl) * 1024 + h * 64;
            aout[base + l31]      = f2bf((o0[r] + Lo[qh][q][l31]) * linv);
            aout[base + 32 + l31] = f2bf((o1[r] + Lo[qh][q][32 + l31]) * linv);
        }
    }
}

// ---------------- proj GEMM: 256x128 tile, BK=64, counted-vmcnt, 16 waves, zero tail ------
// (unchanged from R5)
__global__ __launch_bounds__(1024) void gemm_proj_kernel(const ushort_t* __restrict__ A,
                                                         const ushort_t* __restrict__ Bt,
                                                         const float* __restrict__ bias,
                                                         float* __restrict__ Cout) {
    extern __shared__ __align__(16) ushort_t lds[];

    int bid = blockIdx.x;
    int wg = (bid & 7) * 32 + (bid >> 3);      // XCD-bijective swizzle (256 % 8 == 0)
    int bm = wg & 31, bn = wg >> 5;            // 32 x 8
    int m0 = bm << 8, n0 = bn << 7;

    int tid = threadIdx.x;
    int wave = tid >> 6, lane = tid & 63;
    int c = lane & 15, g = lane >> 4;
    int wm = wave >> 2, wn = wave & 3;

    int row0 = tid >> 3;
    int sch  = (tid & 7) ^ (row0 & 7);
    size_t aoff = (size_t)(m0 + row0) * 1024 + sch * 8;
    size_t boff = (size_t)(n0 + row0) * 1024 + sch * 8;

    int co0 = (g * 8) ^ ((c & 7) << 3);
    int co1 = co0 ^ 32;

    floatx4 acc[4][2];
    short8 a[4][2], bb[2];
#pragma unroll
    for (int i2 = 0; i2 < 4; ++i2)
#pragma unroll
        for (int j2 = 0; j2 < 2; ++j2) { floatx4 z = {0.f,0.f,0.f,0.f}; acc[i2][j2] = z; }

    auto stA = [&](int t, int buf) {
        const ushort_t* s = A + aoff + (size_t)t * 64;
        ushort_t* d = lds + buf * 16384 + tid * 8;
        async_ld16(s, d);
        async_ld16(s + 131072, d + 8192);
    };
    auto stB = [&](int t, int buf) {
        async_ld16(Bt + boff + (size_t)t * 64, lds + 32768 + buf * 8192 + tid * 8);
    };
    auto ld_a = [&](int buf) {
#pragma unroll
        for (int mi = 0; mi < 4; ++mi) {
            int ro = buf * 16384 + (wm * 64 + mi * 16 + c) * 64;
            a[mi][0] = *(const short8*)&lds[ro + co0];
            a[mi][1] = *(const short8*)&lds[ro + co1];
        }
    };
    auto ld_b = [&](int buf, int nii) {
        int ro = 32768 + buf * 8192 + (wn * 32 + nii * 16 + c) * 64;
        bb[0] = *(const short8*)&lds[ro + co0];
        bb[1] = *(const short8*)&lds[ro + co1];
    };
    auto mm = [&](int nii) {
        asm volatile("s_barrier" ::: "memory");
        asm volatile("s_waitcnt lgkmcnt(0)" ::: "memory");
        __builtin_amdgcn_s_setprio(1);
#pragma unroll
        for (int mi = 0; mi < 4; ++mi)
#pragma unroll
            for (int ks = 0; ks < 2; ++ks)
                acc[mi][nii] = __builtin_amdgcn_mfma_f32_16x16x32_bf16(
                    a[mi][ks], bb[ks], acc[mi][nii], 0, 0, 0);
        __builtin_amdgcn_s_setprio(0);
        asm volatile("s_barrier" ::: "memory");
    };

    stA(0, 0); stB(0, 0);
    stA(1, 1); stB(1, 1);
    asm volatile("s_waitcnt vmcnt(3)" ::: "memory");
    asm volatile("s_barrier" ::: "memory");

#pragma unroll 1
    for (int t = 0; t < 14; ++t) {
        int buf = t & 1;
        ld_a(buf); ld_b(buf, 0);
        mm(0);
        ld_b(buf, 1);
        stA(t + 2, buf); stB(t + 2, buf);
        asm volatile("s_waitcnt vmcnt(3)" ::: "memory");
        mm(1);
    }
    ld_a(0); ld_b(0, 0);
    mm(0);
    ld_b(0, 1);
    asm volatile("s_waitcnt vmcnt(0)" ::: "memory");
    mm(1);
    ld_a(1); ld_b(1, 0);
    mm(0);
    ld_b(1, 1);
    mm(1);

    float bv[2];
#pragma unroll
    for (int nii = 0; nii < 2; ++nii) bv[nii] = bias[n0 + wn * 32 + nii * 16 + c];
#pragma unroll
    for (int mi = 0; mi < 4; ++mi)
#pragma unroll
        for (int nii = 0; nii < 2; ++nii)
#pragma unroll
            for (int r = 0; r < 4; ++r) {
                int row = m0 + wm * 64 + mi * 16 + g * 4 + r;
                int col = n0 + wn * 32 + nii * 16 + c;
                Cout[(size_t)row * 1024 + col] = acc[mi][nii][r] + bv[nii];
            }
}

extern "C" void kernel_launch(void* const* d_in, const int* in_sizes, int n_in,
                              void* d_out, int out_size, void* d_ws, size_t ws_size,
                              hipStream_t stream) {
    const float* x        = (const float*)d_in[0];
    const float* c_attn_w = (const float*)d_in[1];
    const float* c_attn_b = (const float*)d_in[2];
    const float* c_proj_w = (const float*)d_in[3];
    const float* c_proj_b = (const float*)d_in[4];
    float* out = (float*)d_out;

    char* ws = (char*)d_ws;
    ushort_t* xb     = (ushort_t*)(ws);              // 16 MB; reused as attn output 'a'
    ushort_t* wqkvT  = (ushort_t*)(ws + 16777216);   // 6 MB
    ushort_t* wprojT = (ushort_t*)(ws + 23068672);   // 2 MB
    ushort_t* qbuf   = (ushort_t*)(ws + 25165824);   // 16 MB  [bh][s][64]  (pre-scaled)
    ushort_t* kbuf   = (ushort_t*)(ws + 41943040);   // 16 MB  [bh][s][64]
    ushort_t* vtbuf  = (ushort_t*)(ws + 58720256);   // 16 MB  [bh][64][2048]

    static bool s_attr_set = false;
    if (!s_attr_set) {
        (void)hipFuncSetAttribute(reinterpret_cast<const void*>(gemm_qkv_kernel),
                                  hipFuncAttributeMaxDynamicSharedMemorySize, 131072);
        (void)hipFuncSetAttribute(reinterpret_cast<const void*>(gemm_proj_kernel),
                                  hipFuncAttributeMaxDynamicSharedMemorySize, 98304);
        s_attr_set = true;
    }

    prep_kernel<<<12288, 256, 0, stream>>>(x, c_attn_w, c_proj_w, xb, wqkvT, wprojT);
    gemm_qkv_kernel<<<512, 1024, 131072, stream>>>(xb, wqkvT, c_attn_b, qbuf, kbuf, vtbuf);
    attn_kernel<<<2048, 256, 0, stream>>>(qbuf, kbuf, vtbuf, xb);
    gemm_proj_kernel<<<256, 1024, 98304, stream>>>(xb, wprojT, c_proj_b, out);
}